// Round 6
// baseline (115.404 us; speedup 1.0000x reference)
//
#include <hip/hip_runtime.h>
#include <hip/hip_bf16.h>
#include <stdint.h>
#include <stddef.h>

// ---------------------------------------------------------------------------
// FixedEmbedderNN — all-linear fold + transposed-MFMA pipeline, round 6:
// column-split waves with REGISTER-PERSISTENT weight fragments.
//   - wave w owns output cols [32w, 32w+32): holds its wl2/wout/a1 fragments
//     in VGPRs for the whole block (loaded once per 128 rows, not per 16).
//   - block = 4 waves, 128 rows processed as 8 groups of 16 rows.
//   - gather: 1 instr per (feature, wave) -- the round-5 permuted tcat layout
//     puts wave w's 32-col slice in one contiguous 64B line per table row.
//   - LN0/LN1 are cross-wave: LDS partial sums (sum, sumsq), 5 barriers/group.
// Precomputed tables (pre1/pre2) are identical to round 5.
// ---------------------------------------------------------------------------

typedef __attribute__((ext_vector_type(8))) short short8;
typedef __attribute__((ext_vector_type(4))) float f32x4;
typedef __attribute__((ext_vector_type(2))) uint32_t uint32x2;

#define LN_EPS 1e-5f

__device__ __forceinline__ float bflo(uint32_t u){ union{uint32_t u;float f;} c; c.u = u<<16; return c.f; }
__device__ __forceinline__ float bfhi(uint32_t u){ union{uint32_t u;float f;} c; c.u = u&0xffff0000u; return c.f; }
__device__ __forceinline__ uint16_t f2bf(float f){
  union{ __hip_bfloat16 h; uint16_t u; } c; c.h = __float2bfloat16(f); return c.u;
}
__device__ __forceinline__ uint32_t pkbf(float lo, float hi){
  return (uint32_t)f2bf(lo) | ((uint32_t)f2bf(hi)<<16);
}

// ---------------- precompute kernel 1 (no deps) ----------------
__global__ __launch_bounds__(128) void pre1(
    const float* __restrict__ W_num, const float* __restrict__ b_num,
    const float* __restrict__ W_in,  const float* __restrict__ b_in,
    const float* __restrict__ W1,    const float* __restrict__ b1,
    const float* __restrict__ W2,    const float* __restrict__ b2,
    const float* __restrict__ W_out, const float* __restrict__ b_out,
    const float* __restrict__ ln_g,  const float* __restrict__ ln_b,
    float* __restrict__ WLf,    // [2][128][128]
    float* __restrict__ Bnum,   // [21][128]
    float* __restrict__ bfold,  // [2][128]
    uint16_t* __restrict__ woutp, // Wout' transposed pack [(t*4+ks)*64+lane][8]
    float* __restrict__ boutp)    // bout' permuted [g*32+t*4+r]
{
  const int b = blockIdx.x, j = threadIdx.x;
  if (b < 256) {                       // WL = W1@W2 per layer
    const int l = b >> 7, k = b & 127;
    const float* w1r = W1 + (l*128 + k)*256;
    const float* w2  = W2 + l*256*128;
    float s = 0.f;
    for (int m = 0; m < 256; m++) s = fmaf(w1r[m], w2[m*128 + j], s);
    WLf[(l*128 + k)*128 + j] = s;
  } else if (b < 277) {                // Bnum rows
    const int r = b - 256;
    if (r < 20) {
      const float* wn = W_num + r*32;
      const float* wi = W_in + (size_t)(20 + r)*32*128;
      float s = 0.f;
      for (int e = 0; e < 32; e++) s = fmaf(wn[e], wi[e*128 + j], s);
      Bnum[r*128 + j] = s;
    } else {
      float s = b_in[j];
      for (int f = 0; f < 20; f++) {
        const float* bn = b_num + f*32;
        const float* wi = W_in + (size_t)(20 + f)*32*128;
        for (int e = 0; e < 32; e++) s = fmaf(bn[e], wi[e*128 + j], s);
      }
      Bnum[20*128 + j] = s;
    }
  } else if (b < 279) {                // bfold = b1@W2 + b2
    const int l = b - 277;
    const float* b1r = b1 + l*256;
    const float* w2  = W2 + l*256*128;
    float s = b2[l*128 + j];
    for (int k = 0; k < 256; k++) s = fmaf(b1r[k], w2[k*128 + j], s);
    bfold[l*128 + j] = s;
  } else if (b < 311) {                // woutp: Wout' = diag(g1)@W_out, transposed A-pack
    const int p = b - 279, t = p >> 2, ks = p & 3;
    const int lane = j & 63, rep = j >> 6;
    const int col = 16*t + (lane & 15);
    for (int ii = 0; ii < 4; ii++) {
      const int i = rep*4 + ii;
      const int k = 32*ks + 8*(lane >> 4) + i;
      woutp[((t*4 + ks)*64 + lane)*8 + i] = f2bf(ln_g[128 + k] * W_out[k*128 + col]);
    }
  } else {                             // boutp (permuted): b1n@W_out + b_out
    const int t = (j >> 2) & 7, g = j >> 5, r = j & 3;
    const int col = 16*t + 4*g + r;
    float s = b_out[col];
    for (int k = 0; k < 128; k++) s = fmaf(ln_b[128 + k], W_out[k*128 + col], s);
    boutp[j] = s;
  }
}

// ---------------- precompute kernel 2 (depends on pre1) ----------------
__global__ __launch_bounds__(128) void pre2(
    const float* __restrict__ emb, const float* __restrict__ W_in,
    const float* __restrict__ ln_g, const float* __restrict__ ln_b,
    const float* __restrict__ WLf, const float* __restrict__ Bnum,
    const float* __restrict__ bfold,
    uint16_t* __restrict__ tcatp, // [20][50][128] bf16, line-optimal permuted cols
    uint16_t* __restrict__ wl2p,  // WL1' transposed pack
    float* __restrict__ bf1p,     // bf1' permuted
    uint16_t* __restrict__ a1p)   // A1^T A-frag pack [t*64+lane][8]
{
  const int b = blockIdx.x, j = threadIdx.x;
  __shared__ float sh[128];
  if (b < 1000) {                      // Tcat1 = emb@W_in_slice@WL_0, permuted store
    const int f = b / 50, c = b % 50;
    const float* e  = emb + (f*50 + c)*32;
    const float* wi = W_in + (size_t)f*32*128;
    float s = 0.f;
    for (int k = 0; k < 32; k++) s = fmaf(e[k], wi[k*128 + j], s);
    sh[j] = s;
    __syncthreads();
    float s2 = 0.f;
    for (int k = 0; k < 128; k++) s2 = fmaf(sh[k], WLf[k*128 + j], s2);
    // col j = 16t+4g+r  ->  pos = (t>>1)*32 + g*8 + (t&1)*4 + r  (line-optimal)
    const int t = j >> 4, g = (j >> 2) & 3, r = j & 3;
    const int pos = ((t >> 1) << 5) | (g << 3) | ((t & 1) << 2) | r;
    tcatp[(f*50 + c)*128 + pos] = f2bf(s2);
  } else if (b < 1032) {               // wl2p: WL1' = diag(g0)@WL_1, transposed A-pack
    const int p = b - 1000, t = p >> 2, ks = p & 3;
    const int lane = j & 63, rep = j >> 6;
    const int col = 16*t + (lane & 15);
    const float* wl1 = WLf + 16384;
    for (int ii = 0; ii < 4; ii++) {
      const int i = rep*4 + ii;
      const int k = 32*ks + 8*(lane >> 4) + i;
      wl2p[((t*4 + ks)*64 + lane)*8 + i] = f2bf(ln_g[k] * wl1[k*128 + col]);
    }
  } else if (b == 1032) {              // bf1p (permuted): b0@WL_1 + bfold_1
    const int t = (j >> 2) & 7, g = j >> 5, r = j & 3;
    const int col = 16*t + 4*g + r;
    const float* wl1 = WLf + 16384;
    float s = bfold[128 + col];
    for (int k = 0; k < 128; k++) s = fmaf(ln_b[k], wl1[k*128 + col], s);
    bf1p[j] = s;
  } else {                             // a1p: A1[k][col] = Bnum[k]@WL_0 (+bfold0 @k==20)
    const int t = b - 1033;
    const int lane = j & 63, rep = j >> 6;
    const int col = 16*t + (lane & 15);
    for (int ii = 0; ii < 4; ii++) {
      const int i = rep*4 + ii;
      const int k = 8*(lane >> 4) + i;
      float v = 0.f;
      if (k <= 20) {
        if (k == 20) v = bfold[col];
        for (int m = 0; m < 128; m++) v = fmaf(Bnum[k*128 + m], WLf[m*128 + col], v);
      }
      a1p[(t*64 + lane)*8 + i] = f2bf(v);
    }
  }
}

// ---------------- main fused kernel ----------------
// block = 256 thr (4 waves); wave owns 32 output cols; block = 128 rows in
// 8 groups of 16. Weight frags register-persistent per block.
__global__ __launch_bounds__(256, 3) void fused_main(
    const float* __restrict__ x,
    const uint16_t* __restrict__ tcatp,
    const uint16_t* __restrict__ a1p,
    const uint16_t* __restrict__ wl2p,
    const uint16_t* __restrict__ woutp,
    const float* __restrict__ bf1p,
    const float* __restrict__ boutp,
    float* __restrict__ out)
{
  __shared__ float xs[16*41];                        // x tile (16 rows)
  __shared__ __align__(16) uint16_t hbuf[16*136];    // z roundtrip, stride 136
  __shared__ float2 part[4][16];                     // per-wave LN partials
  const int tid = threadIdx.x, lane = tid & 63, w = tid >> 6;
  const int g = lane >> 4, c16 = lane & 15;

  // ---- persistent weight fragments for this wave's 2 col-tiles (t=2w+jj) ----
  short8 wl2f[2][4], wof[2][4], a1f[2];
  #pragma unroll
  for (int jj = 0; jj < 2; jj++) {
    const int t = 2*w + jj;
    a1f[jj] = *reinterpret_cast<const short8*>(a1p + (t*64 + lane)*8);
    #pragma unroll
    for (int ks = 0; ks < 4; ks++) {
      wl2f[jj][ks] = *reinterpret_cast<const short8*>(wl2p + ((t*4 + ks)*64 + lane)*8);
      wof[jj][ks]  = *reinterpret_cast<const short8*>(woutp + ((t*4 + ks)*64 + lane)*8);
    }
  }

  const char* tcb = (const char*)tcatp + (uint32_t)(w*64 + g*16);
  const float* xr = xs + c16*41;

  for (int grp = 0; grp < 8; grp++) {
    const int rowbase = blockIdx.x*128 + grp*16;

    // ---- stage 16 rows of x (cooperative, 640 floats) ----
    {
      const float* xsrc = x + (size_t)rowbase*40;
      for (int i = tid; i < 640; i += 256) xs[(i/40)*41 + (i%40)] = xsrc[i];
    }
    __syncthreads();                                   // #1

    // ---- numeric part via MFMA: acc[jj] = cols 16(2w+jj)+4g+r of row c16 ----
    short8 xf;
    #pragma unroll
    for (int i = 0; i < 8; i++) {
      const int k = 8*g + i;
      float v = (k < 20) ? xr[20 + k] : (k == 20 ? 1.0f : 0.0f);
      ((uint16_t*)&xf)[i] = f2bf(v);
    }
    f32x4 acc[2];
    #pragma unroll
    for (int jj = 0; jj < 2; jj++)
      acc[jj] = __builtin_amdgcn_mfma_f32_16x16x32_bf16(a1f[jj], xf,
                                                        (f32x4){0.f,0.f,0.f,0.f}, 0, 0, 0);

    // ---- gather: 1 instr per feature (wave's 64B slice = 1 line), 4-deep ----
#define GLD(f) (*reinterpret_cast<const uint4*>(tcb + ((f)*50 + (int)xr[f])*256u))
    {
      uint4 rg[4];
      #pragma unroll
      for (int i = 0; i < 4; i++) rg[i] = GLD(i);
      #pragma unroll
      for (int fb = 0; fb < 20; fb += 4) {
        uint4 nx[4];
        if (fb + 4 < 20) {
          #pragma unroll
          for (int i = 0; i < 4; i++) nx[i] = GLD(fb + 4 + i);
        }
        #pragma unroll
        for (int i = 0; i < 4; i++) {
          const uint4 u = rg[i];
          acc[0][0] += bflo(u.x); acc[0][1] += bfhi(u.x);
          acc[0][2] += bflo(u.y); acc[0][3] += bfhi(u.y);
          acc[1][0] += bflo(u.z); acc[1][1] += bfhi(u.z);
          acc[1][2] += bflo(u.w); acc[1][3] += bfhi(u.w);
        }
        if (fb + 4 < 20) {
          #pragma unroll
          for (int i = 0; i < 4; i++) rg[i] = nx[i];
        }
      }
    }
#undef GLD

    // ---- LN0 cross-wave: partials (sum, sumsq) ----
    {
      float s = 0.f, q = 0.f;
      #pragma unroll
      for (int jj = 0; jj < 2; jj++)
        #pragma unroll
        for (int r = 0; r < 4; r++) { const float v = acc[jj][r]; s += v; q = fmaf(v, v, q); }
      s += __shfl_xor(s, 16); s += __shfl_xor(s, 32);
      q += __shfl_xor(q, 16); q += __shfl_xor(q, 32);
      if ((lane & 48) == 0) part[w][c16] = make_float2(s, q);
    }
    __syncthreads();                                   // #2
    {
      float S = 0.f, Q = 0.f;
      #pragma unroll
      for (int ww = 0; ww < 4; ww++) { const float2 p = part[ww][c16]; S += p.x; Q += p.y; }
      const float mu = S * (1.f/128.f);
      const float rs = rsqrtf(Q*(1.f/128.f) - mu*mu + LN_EPS);
      #pragma unroll
      for (int jj = 0; jj < 2; jj++) {
        const uint32x2 v = { pkbf((acc[jj][0]-mu)*rs, (acc[jj][1]-mu)*rs),
                             pkbf((acc[jj][2]-mu)*rs, (acc[jj][3]-mu)*rs) };
        *reinterpret_cast<uint32x2*>(hbuf + c16*136 + 16*(2*w + jj) + 4*g) = v;
      }
    }
    __syncthreads();                                   // #3

    // ---- GEMM2': acc2[jj] = z1 @ WL1' (+ bf1') ----
    short8 a2[4];
    #pragma unroll
    for (int ks = 0; ks < 4; ks++)
      a2[ks] = *reinterpret_cast<const short8*>(hbuf + c16*136 + 32*ks + 8*g);
    f32x4 acc2[2];
    #pragma unroll
    for (int jj = 0; jj < 2; jj++) {
      acc2[jj] = *reinterpret_cast<const f32x4*>(bf1p + g*32 + (2*w + jj)*4);
      #pragma unroll
      for (int ks = 0; ks < 4; ks++)
        acc2[jj] = __builtin_amdgcn_mfma_f32_16x16x32_bf16(wl2f[jj][ks], a2[ks], acc2[jj], 0, 0, 0);
    }

    // ---- LN1 cross-wave ----
    {
      float s = 0.f, q = 0.f;
      #pragma unroll
      for (int jj = 0; jj < 2; jj++)
        #pragma unroll
        for (int r = 0; r < 4; r++) { const float v = acc2[jj][r]; s += v; q = fmaf(v, v, q); }
      s += __shfl_xor(s, 16); s += __shfl_xor(s, 32);
      q += __shfl_xor(q, 16); q += __shfl_xor(q, 32);
      if ((lane & 48) == 0) part[w][c16] = make_float2(s, q);
    }
    __syncthreads();                                   // #4
    {
      float S = 0.f, Q = 0.f;
      #pragma unroll
      for (int ww = 0; ww < 4; ww++) { const float2 p = part[ww][c16]; S += p.x; Q += p.y; }
      const float mu = S * (1.f/128.f);
      const float rs = rsqrtf(Q*(1.f/128.f) - mu*mu + LN_EPS);
      #pragma unroll
      for (int jj = 0; jj < 2; jj++) {
        const uint32x2 v = { pkbf((acc2[jj][0]-mu)*rs, (acc2[jj][1]-mu)*rs),
                             pkbf((acc2[jj][2]-mu)*rs, (acc2[jj][3]-mu)*rs) };
        *reinterpret_cast<uint32x2*>(hbuf + c16*136 + 16*(2*w + jj) + 4*g) = v;
      }
    }
    __syncthreads();                                   // #5

    // ---- GEMM3': out = z2 @ Wout' + bout' ----
    short8 a3[4];
    #pragma unroll
    for (int ks = 0; ks < 4; ks++)
      a3[ks] = *reinterpret_cast<const short8*>(hbuf + c16*136 + 32*ks + 8*g);
    const size_t orow = (size_t)(rowbase + c16)*128;
    #pragma unroll
    for (int jj = 0; jj < 2; jj++) {
      f32x4 a3c = *reinterpret_cast<const f32x4*>(boutp + g*32 + (2*w + jj)*4);
      #pragma unroll
      for (int ks = 0; ks < 4; ks++)
        a3c = __builtin_amdgcn_mfma_f32_16x16x32_bf16(wof[jj][ks], a3[ks], a3c, 0, 0, 0);
      __builtin_nontemporal_store(a3c,
          reinterpret_cast<f32x4*>(out + orow + 32*w + 16*jj + 4*g));
    }
    __syncthreads();                                   // protect xs/hbuf reuse
  }
}

// ---------------- launcher ----------------
extern "C" void kernel_launch(void* const* d_in, const int* in_sizes, int n_in,
                              void* d_out, int out_size, void* d_ws, size_t ws_size,
                              hipStream_t stream)
{
  const float* x     = (const float*)d_in[0];
  const float* emb   = (const float*)d_in[1];
  const float* W_num = (const float*)d_in[2];
  const float* b_num = (const float*)d_in[3];
  const float* W_in  = (const float*)d_in[4];
  const float* b_in  = (const float*)d_in[5];
  const float* W1    = (const float*)d_in[6];
  const float* b1    = (const float*)d_in[7];
  const float* W2    = (const float*)d_in[8];
  const float* b2    = (const float*)d_in[9];
  const float* ln_g  = (const float*)d_in[10];
  const float* ln_b  = (const float*)d_in[11];
  const float* W_out = (const float*)d_in[12];
  const float* b_out = (const float*)d_in[13];
  float* out = (float*)d_out;

  char* ws = (char*)d_ws;
  float*    WLf   = (float*)(ws + 0);         // 131072 B
  float*    Bnum  = (float*)(ws + 131072);    //  10752 B
  float*    bfold = (float*)(ws + 141824);    //   1024 B
  uint16_t* tcatp = (uint16_t*)(ws + 142848); // 256000 B
  uint16_t* wl2p  = (uint16_t*)(ws + 398848); //  32768 B
  uint16_t* woutp = (uint16_t*)(ws + 431616); //  32768 B
  uint16_t* a1p   = (uint16_t*)(ws + 464384); //   8192 B
  float*    bf1p  = (float*)(ws + 472576);    //    512 B
  float*    boutp = (float*)(ws + 473088);    //    512 B

  const int nrows = in_sizes[0] / 40;         // 98304
  const int grid  = nrows / 128;              // 768 = 3 blocks/CU

  pre1<<<dim3(312), dim3(128), 0, stream>>>(W_num, b_num, W_in, b_in, W1, b1, W2, b2,
                                            W_out, b_out, ln_g, ln_b,
                                            WLf, Bnum, bfold, woutp, boutp);
  pre2<<<dim3(1041), dim3(128), 0, stream>>>(emb, W_in, ln_g, ln_b, WLf, Bnum, bfold,
                                             tcatp, wl2p, bf1p, a1p);
  fused_main<<<dim3(grid), dim3(256), 0, stream>>>(x, tcatp, a1p, wl2p, woutp,
                                                   bf1p, boutp, out);
}